// Round 4
// baseline (1927.130 us; speedup 1.0000x reference)
//
#include <hip/hip_runtime.h>

// APPNP: out = log_softmax(z_K), z_{k+1} = 0.9*A z_k + 0.1*h, z0 = h
// h = relu(x@W1+b1)@W2 + b2
// DTYPE-ADAPTIVE: float arrays may be fp32 or bf16; detected on-device from x's
// bit patterns (flag in ws). All float-input loads and the final output store
// branch on the flag. z/h/cs_val precision picked host-side from ws_size.

typedef unsigned short ushort_t;
typedef short short8 __attribute__((ext_vector_type(8)));
typedef float f32x4 __attribute__((ext_vector_type(4)));

#define NFEAT 512
#define NHID 256
#define NCLASS 40

static __device__ __forceinline__ float b2f(ushort_t u) {
    unsigned v = ((unsigned)u) << 16;
    float f;
    __builtin_memcpy(&f, &v, 4);
    return f;
}
static __device__ __forceinline__ ushort_t f2b(float f) {
    unsigned u;
    __builtin_memcpy(&u, &f, 4);
    unsigned r = u + 0x7FFFu + ((u >> 16) & 1u);
    return (ushort_t)(r >> 16);
}
static __device__ __forceinline__ ushort_t san_u(ushort_t u) {
    return ((u & 0x7F80u) == 0x7F80u) ? (ushort_t)0 : u;
}
// mixed-dtype primary-input load (sanitized on bf16 path)
static __device__ __forceinline__ float ldmix(const void* p, size_t i, int isbf) {
    if (isbf) return b2f(san_u(((const ushort_t*)p)[i]));
    return ((const float*)p)[i];
}
// z/h/cs_val scratch accessors (dtype chosen by host flag zbf)
static __device__ __forceinline__ float ldz(const void* p, size_t i, int zbf) {
    return zbf ? b2f(((const ushort_t*)p)[i]) : ((const float*)p)[i];
}
static __device__ __forceinline__ void stz(void* p, size_t i, int zbf, float v) {
    if (zbf) ((ushort_t*)p)[i] = f2b(v);
    else ((float*)p)[i] = v;
}

// ---------------- dtype detect ----------------
// Even-indexed u16 of x: genuine bf16 -> exponent near 127 (N(0,1) data);
// fp32 data -> low mantissa halves, uniform bits -> ~14% in window.
__global__ void detect_kernel(const ushort_t* __restrict__ x, int* __restrict__ flag) {
    __shared__ int cnt_s;
    if (threadIdx.x == 0) cnt_s = 0;
    __syncthreads();
    int c = 0;
    for (int i = threadIdx.x; i < 2048; i += 256) {
        ushort_t u = x[2 * i];
        int e = (u >> 7) & 0xFF;
        if (e >= 107 && e <= 141) c++;
    }
    atomicAdd(&cnt_s, c);
    __syncthreads();
    if (threadIdx.x == 0) flag[0] = (cnt_s >= 1024) ? 1 : 0;
}

// ---------------- CSR build ----------------

__global__ void zero_kernel(int* __restrict__ p, int n) {
    int i = blockIdx.x * 256 + threadIdx.x;
    if (i < n) p[i] = 0;
}

__global__ void hist_kernel(const int* __restrict__ row, int* __restrict__ deg, int e, int n) {
    int i = blockIdx.x * 256 + threadIdx.x;
    if (i < e) {
        int r = row[i];
        if ((unsigned)r < (unsigned)n) atomicAdd(&deg[r], 1);
    }
}

__global__ void scan_simple(const int* __restrict__ deg, int* __restrict__ row_start,
                            int* __restrict__ cursor, int n) {
    __shared__ int s[1024];
    __shared__ int carry_s;
    int t = threadIdx.x;
    if (t == 0) carry_s = 0;
    __syncthreads();
    for (int base = 0; base < n; base += 1024) {
        int i = base + t;
        int v = (i < n) ? deg[i] : 0;
        int own = v;
        s[t] = v;
        __syncthreads();
        for (int o = 1; o < 1024; o <<= 1) {
            int add = (t >= o) ? s[t - o] : 0;
            __syncthreads();
            s[t] += add;
            __syncthreads();
        }
        if (i < n) {
            int rs = carry_s + s[t] - own;
            row_start[i] = rs;
            cursor[i] = rs;
        }
        __syncthreads();
        if (t == 1023) carry_s += s[1023];
        __syncthreads();
    }
}

__global__ void scatter_kernel(const int* __restrict__ row, const int* __restrict__ col,
                               const void* __restrict__ vals, int* __restrict__ cursor,
                               int* __restrict__ cs_col, void* __restrict__ cs_val,
                               const int* __restrict__ flag, int zbf, int e, int n) {
    int i = blockIdx.x * 256 + threadIdx.x;
    if (i < e) {
        int isbf = flag[0];
        int r = row[i];
        if ((unsigned)r >= (unsigned)n) return;
        int p = atomicAdd(&cursor[r], 1);
        if ((unsigned)p < (unsigned)e) {
            int c = col[i];
            cs_col[p] = ((unsigned)c < (unsigned)n) ? c : 0;
            stz(cs_val, p, zbf, ldmix(vals, i, isbf));
        }
    }
}

// ---------------- weight fragment pre-layout (canonical bf16) ----------------
// B-frag (mfma_f32_16x16x32_bf16): lane l holds B[k=(l>>4)*8+j][n=l&15], j=0..7.

__global__ void w1frag_kernel(const void* __restrict__ W1, ushort_t* __restrict__ w1f,
                              const int* __restrict__ flag) {
    int t = blockIdx.x * 256 + threadIdx.x;  // 16384 total
    if (t >= 16 * 16 * 64) return;
    int isbf = flag[0];
    int l = t & 63, nt = (t >> 6) & 15, kb = t >> 10;
    ushort_t tmp[8];
#pragma unroll
    for (int j = 0; j < 8; j++) {
        int k = kb * 32 + (l >> 4) * 8 + j;
        int nn = nt * 16 + (l & 15);
        tmp[j] = f2b(ldmix(W1, (size_t)k * NHID + nn, isbf));
    }
    *(short8*)(w1f + (size_t)t * 8) = *(short8*)tmp;
}

__global__ void w2frag_kernel(const void* __restrict__ W2, ushort_t* __restrict__ w2f,
                              const int* __restrict__ flag) {
    int t = blockIdx.x * 256 + threadIdx.x;  // 1536 total
    if (t >= 8 * 3 * 64) return;
    int isbf = flag[0];
    int l = t % 64;
    int nt = (t / 64) % 3;
    int kb = t / 192;
    ushort_t tmp[8];
#pragma unroll
    for (int j = 0; j < 8; j++) {
        int k = kb * 32 + (l >> 4) * 8 + j;
        int nn = nt * 16 + (l & 15);
        tmp[j] = (nn < NCLASS) ? f2b(ldmix(W2, (size_t)k * NCLASS + nn, isbf)) : (ushort_t)0;
    }
    *(short8*)(w2f + (size_t)t * 8) = *(short8*)tmp;
}

// ---------------- fused MLP: h = relu(x@W1+b1)@W2 + b2 ----------------

__global__ __launch_bounds__(256) void mlp_kernel(const void* __restrict__ x,
                                                  const ushort_t* __restrict__ w1f,
                                                  const ushort_t* __restrict__ w2f,
                                                  const void* __restrict__ b1,
                                                  const void* __restrict__ b2,
                                                  void* __restrict__ h,
                                                  const int* __restrict__ flag, int zbf, int n) {
    __shared__ ushort_t Alds[64][40];   // 80B pitch
    __shared__ ushort_t Hlds[64][264];  // 528B pitch, 256 cols used
    const int t = threadIdx.x;
    const int isbf = flag[0];
    const int wv = t >> 6, l = t & 63;
    const int lq = l >> 4, lr = l & 15;
    const int m0 = blockIdx.x * 64;

    f32x4 acc[16];
#pragma unroll
    for (int i = 0; i < 16; i++) acc[i] = (f32x4){0.f, 0.f, 0.f, 0.f};

    const int rS = t >> 2, qS = t & 3;
    int rowS = m0 + rS;
    if (rowS > n - 1) rowS = n - 1;
    const size_t xbase = (size_t)rowS * NFEAT + qS * 8;
    const ushort_t* aldsp = &Alds[wv * 16 + lr][lq * 8];

    for (int kb = 0; kb < 16; kb++) {
        short8 av;
        if (isbf) {
            av = *(const short8*)((const ushort_t*)x + xbase + kb * 32);
#pragma unroll
            for (int j = 0; j < 8; j++) {
                ushort_t u = (ushort_t)av[j];
                if ((u & 0x7F80u) == 0x7F80u) av[j] = 0;
            }
        } else {
            const float* xf = (const float*)x + xbase + kb * 32;
            f32x4 a0 = *(const f32x4*)xf;
            f32x4 a1 = *(const f32x4*)(xf + 4);
#pragma unroll
            for (int j = 0; j < 4; j++) {
                av[j] = (short)f2b(a0[j]);
                av[4 + j] = (short)f2b(a1[j]);
            }
        }
        *(short8*)&Alds[rS][qS * 8] = av;
        __syncthreads();
        short8 afrag = *(const short8*)aldsp;
        const ushort_t* bp = w1f + ((size_t)(kb * 16) * 64 + l) * 8;
#pragma unroll
        for (int nt = 0; nt < 16; nt++) {
            short8 bfrag = *(const short8*)(bp + (size_t)nt * 64 * 8);
            acc[nt] = __builtin_amdgcn_mfma_f32_16x16x32_bf16(afrag, bfrag, acc[nt], 0, 0, 0);
        }
        __syncthreads();
    }

    // stage-1 epilogue -> LDS (D: row=(lane>>4)*4+reg, col=lane&15)
    float bias1 = ldmix(b1, 0, isbf);
#pragma unroll
    for (int nt = 0; nt < 16; nt++) {
#pragma unroll
        for (int i = 0; i < 4; i++) {
            float v = acc[nt][i] + bias1;
            v = fmaxf(v, 0.f);
            Hlds[wv * 16 + lq * 4 + i][nt * 16 + lr] = f2b(v);
        }
    }
    __syncthreads();

    // stage 2: A-frag = Hlds[wv*16+lr][kb*32 + lq*8 + j]
    f32x4 acc2[3];
#pragma unroll
    for (int i = 0; i < 3; i++) acc2[i] = (f32x4){0.f, 0.f, 0.f, 0.f};
    const ushort_t* hp = &Hlds[wv * 16 + lr][lq * 8];
#pragma unroll
    for (int kb = 0; kb < 8; kb++) {
        short8 afrag = *(const short8*)(hp + kb * 32);
#pragma unroll
        for (int nt = 0; nt < 3; nt++) {
            short8 bfrag = *(const short8*)(w2f + ((size_t)(kb * 3 + nt) * 64 + l) * 8);
            acc2[nt] = __builtin_amdgcn_mfma_f32_16x16x32_bf16(afrag, bfrag, acc2[nt], 0, 0, 0);
        }
    }

    float bias2 = ldmix(b2, 0, isbf);
#pragma unroll
    for (int nt = 0; nt < 3; nt++) {
#pragma unroll
        for (int i = 0; i < 4; i++) {
            int rowg = m0 + wv * 16 + lq * 4 + i;
            int colg = nt * 16 + lr;
            if (rowg < n && colg < NCLASS)
                stz(h, (size_t)rowg * NCLASS + colg, zbf, acc2[nt][i] + bias2);
        }
    }
}

// ---------------- propagation: zout = 0.9 * A zin + 0.1 * h ----------------

__global__ __launch_bounds__(256) void prop_kernel(const void* __restrict__ zin,
                                                   void* __restrict__ zout,
                                                   const void* __restrict__ h,
                                                   const int* __restrict__ row_start,
                                                   const int* __restrict__ deg,
                                                   const int* __restrict__ cs_col,
                                                   const void* __restrict__ cs_val, int zbf,
                                                   int n) {
    int w = blockIdx.x * 4 + (threadIdx.x >> 6);
    int lane = threadIdx.x & 63;
    if (w >= n) return;
    int start = row_start[w];
    int d = deg[w];
    float acc = 0.f;
    for (int base = 0; base < d; base += 64) {
        int m = d - base;
        if (m > 64) m = 64;
        int c = 0;
        float v = 0.f;
        if (lane < m) {
            c = cs_col[start + base + lane];
            v = ldz(cs_val, (size_t)start + base + lane, zbf);
        }
        for (int j = 0; j < m; j++) {
            int cc = __shfl(c, j);
            float vv = __shfl(v, j);
            if ((unsigned)cc < (unsigned)n && lane < NCLASS)
                acc += vv * ldz(zin, (size_t)cc * NCLASS + lane, zbf);
        }
    }
    if (lane < NCLASS) {
        float hv = ldz(h, (size_t)w * NCLASS + lane, zbf);
        stz(zout, (size_t)w * NCLASS + lane, zbf, 0.9f * acc + 0.1f * hv);
    }
}

// ---------------- log_softmax; out dtype follows detected input dtype ---------

__global__ __launch_bounds__(256) void lsm_kernel(const void* __restrict__ z,
                                                  void* __restrict__ out,
                                                  const int* __restrict__ flag, int zbf, int n) {
    int w = blockIdx.x * 4 + (threadIdx.x >> 6);
    int lane = threadIdx.x & 63;
    if (w >= n) return;
    int isbf = flag[0];
    float v = (lane < NCLASS) ? ldz(z, (size_t)w * NCLASS + lane, zbf) : -INFINITY;
    float m = v;
    for (int o = 32; o; o >>= 1) m = fmaxf(m, __shfl_xor(m, o));
    float e = (lane < NCLASS) ? __expf(v - m) : 0.f;
    float s = e;
    for (int o = 32; o; o >>= 1) s += __shfl_xor(s, o);
    if (lane < NCLASS) {
        float r = v - m - __logf(s);
        if (isbf) ((ushort_t*)out)[(size_t)w * NCLASS + lane] = f2b(r);
        else ((float*)out)[(size_t)w * NCLASS + lane] = r;
    }
}

// ---------------- launch ----------------

extern "C" void kernel_launch(void* const* d_in, const int* in_sizes, int n_in, void* d_out,
                              int out_size, void* d_ws, size_t ws_size, hipStream_t stream) {
    const void* x = d_in[0];
    const int* row = (const int*)d_in[1];
    const int* col = (const int*)d_in[2];
    const void* vals = d_in[3];
    const void* W1 = d_in[4];
    const void* b1 = d_in[5];
    const void* W2 = d_in[6];
    const void* b2 = d_in[7];

    const int N = in_sizes[0] / NFEAT;  // 100000
    const int E = in_sizes[1];          // 1600000

    // host-side precision choice for scratch (z/h/cs_val) based on ws_size
    const int roomy = (ws_size == 0) || (ws_size >= (size_t)66 * 1024 * 1024);
    const int zbf = roomy ? 0 : 1;      // 0: fp32 scratch, 1: bf16 scratch
    const size_t ez = roomy ? 4 : 2;

    char* ws = (char*)d_ws;
    size_t off = 0;
    auto take = [&](size_t bytes) {
        size_t o = off;
        off = (off + bytes + 255) & ~(size_t)255;
        return (void*)(ws + o);
    };
    void* h = take((size_t)N * NCLASS * ez);
    void* zA = take((size_t)N * NCLASS * ez);
    void* zB = take((size_t)N * NCLASS * ez);
    int* cs_col = (int*)take((size_t)E * 4);
    void* cs_val = take((size_t)E * ez);
    int* deg = (int*)take((size_t)N * 4);
    int* row_start = (int*)take((size_t)N * 4);
    int* cursor = (int*)take((size_t)N * 4);
    ushort_t* w1f = (ushort_t*)take((size_t)NFEAT * NHID * 2);
    ushort_t* w2f = (ushort_t*)take((size_t)8 * 3 * 64 * 8 * 2);
    int* flag = (int*)take(256);

    const int EB = (E + 255) / 256;
    const int GB = (N + 63) / 64;
    const int PB = (N + 3) / 4;

    detect_kernel<<<1, 256, 0, stream>>>((const ushort_t*)x, flag);

    // CSR build
    zero_kernel<<<(N + 255) / 256, 256, 0, stream>>>(deg, N);
    hist_kernel<<<EB, 256, 0, stream>>>(row, deg, E, N);
    scan_simple<<<1, 1024, 0, stream>>>(deg, row_start, cursor, N);
    scatter_kernel<<<EB, 256, 0, stream>>>(row, col, vals, cursor, cs_col, cs_val, flag, zbf, E,
                                           N);

    // weight fragments (canonical bf16)
    w1frag_kernel<<<64, 256, 0, stream>>>(W1, w1f, flag);
    w2frag_kernel<<<6, 256, 0, stream>>>(W2, w2f, flag);

    // fused MLP -> h
    mlp_kernel<<<GB, 256, 0, stream>>>(x, w1f, w2f, b1, b2, h, flag, zbf, N);

    // 10 propagation steps: h -> zA, then ping-pong zA/zB (ends in zB)
    prop_kernel<<<PB, 256, 0, stream>>>(h, zA, h, row_start, deg, cs_col, cs_val, zbf, N);
    const void* zi = zA;
    void* zo = zB;
    for (int s = 1; s < 10; s++) {
        prop_kernel<<<PB, 256, 0, stream>>>(zi, zo, h, row_start, deg, cs_col, cs_val, zbf, N);
        const void* tmp = zi;
        zi = zo;
        zo = (void*)tmp;
    }
    lsm_kernel<<<PB, 256, 0, stream>>>(zi, d_out, flag, zbf, N);
}

// Round 5
// 1138.769 us; speedup vs baseline: 1.6923x; 1.6923x over previous
//
#include <hip/hip_runtime.h>

// APPNP: out = log_softmax(z_K), z_{k+1} = 0.9*A z_k + 0.1*h, z0 = h
// h = relu(x@W1+b1)@W2 + b2
// DTYPE-ADAPTIVE: float arrays may be fp32 or bf16; detected on-device from x's
// bit patterns (flag in ws). All float-input loads and the final output store
// branch on the flag. z/h/cs_val precision picked host-side from ws_size.

typedef unsigned short ushort_t;
typedef short short8 __attribute__((ext_vector_type(8)));
typedef float f32x4 __attribute__((ext_vector_type(4)));

#define NFEAT 512
#define NHID 256
#define NCLASS 40

static __device__ __forceinline__ float b2f(ushort_t u) {
    unsigned v = ((unsigned)u) << 16;
    float f;
    __builtin_memcpy(&f, &v, 4);
    return f;
}
static __device__ __forceinline__ ushort_t f2b(float f) {
    unsigned u;
    __builtin_memcpy(&u, &f, 4);
    unsigned r = u + 0x7FFFu + ((u >> 16) & 1u);
    return (ushort_t)(r >> 16);
}
static __device__ __forceinline__ ushort_t san_u(ushort_t u) {
    return ((u & 0x7F80u) == 0x7F80u) ? (ushort_t)0 : u;
}
static __device__ __forceinline__ float ldmix(const void* p, size_t i, int isbf) {
    if (isbf) return b2f(san_u(((const ushort_t*)p)[i]));
    return ((const float*)p)[i];
}
static __device__ __forceinline__ float ldz(const void* p, size_t i, int zbf) {
    return zbf ? b2f(((const ushort_t*)p)[i]) : ((const float*)p)[i];
}
static __device__ __forceinline__ void stz(void* p, size_t i, int zbf, float v) {
    if (zbf) ((ushort_t*)p)[i] = f2b(v);
    else ((float*)p)[i] = v;
}

// ---------------- dtype detect ----------------
__global__ void detect_kernel(const ushort_t* __restrict__ x, int* __restrict__ flag) {
    __shared__ int cnt_s;
    if (threadIdx.x == 0) cnt_s = 0;
    __syncthreads();
    int c = 0;
    for (int i = threadIdx.x; i < 2048; i += 256) {
        ushort_t u = x[2 * i];
        int e = (u >> 7) & 0xFF;
        if (e >= 107 && e <= 141) c++;
    }
    atomicAdd(&cnt_s, c);
    __syncthreads();
    if (threadIdx.x == 0) flag[0] = (cnt_s >= 1024) ? 1 : 0;
}

// ---------------- CSR build ----------------

__global__ void zero_kernel(int* __restrict__ p, int n) {
    int i = blockIdx.x * 256 + threadIdx.x;
    if (i < n) p[i] = 0;
}

__global__ void hist_kernel(const int* __restrict__ row, int* __restrict__ deg, int e, int n) {
    int i = blockIdx.x * 256 + threadIdx.x;
    if (i < e) {
        int r = row[i];
        if ((unsigned)r < (unsigned)n) atomicAdd(&deg[r], 1);
    }
}

// multi-block exclusive scan, 3 kernels (NB <= 512)
__global__ void scan_blocksum(const int* __restrict__ deg, int* __restrict__ bsum, int n) {
    __shared__ int s[256];
    int t = threadIdx.x;
    int i = blockIdx.x * 256 + t;
    s[t] = (i < n) ? deg[i] : 0;
    __syncthreads();
    for (int o = 128; o; o >>= 1) {
        if (t < o) s[t] += s[t + o];
        __syncthreads();
    }
    if (t == 0) bsum[blockIdx.x] = s[0];
}

__global__ void scan_bsum_excl(int* __restrict__ bsum, int nb) {
    __shared__ int s[512];
    int t = threadIdx.x;
    int v = (t < nb) ? bsum[t] : 0;
    int own = v;
    s[t] = v;
    __syncthreads();
    for (int o = 1; o < 512; o <<= 1) {
        int add = (t >= o) ? s[t - o] : 0;
        __syncthreads();
        s[t] += add;
        __syncthreads();
    }
    if (t < nb) bsum[t] = s[t] - own;
}

__global__ void scan_emit(const int* __restrict__ deg, const int* __restrict__ bsum,
                          int* __restrict__ row_start, int* __restrict__ cursor, int n) {
    __shared__ int s[256];
    int t = threadIdx.x;
    int i = blockIdx.x * 256 + t;
    int v = (i < n) ? deg[i] : 0;
    int own = v;
    s[t] = v;
    __syncthreads();
    for (int o = 1; o < 256; o <<= 1) {
        int add = (t >= o) ? s[t - o] : 0;
        __syncthreads();
        s[t] += add;
        __syncthreads();
    }
    if (i < n) {
        int rs = bsum[blockIdx.x] + s[t] - own;
        row_start[i] = rs;
        cursor[i] = rs;
    }
}

__global__ void scatter_kernel(const int* __restrict__ row, const int* __restrict__ col,
                               const void* __restrict__ vals, int* __restrict__ cursor,
                               int* __restrict__ cs_col, void* __restrict__ cs_val,
                               const int* __restrict__ flag, int zbf, int e, int n) {
    int i = blockIdx.x * 256 + threadIdx.x;
    if (i < e) {
        int isbf = flag[0];
        int r = row[i];
        if ((unsigned)r >= (unsigned)n) return;
        int p = atomicAdd(&cursor[r], 1);
        if ((unsigned)p < (unsigned)e) {
            int c = col[i];
            cs_col[p] = ((unsigned)c < (unsigned)n) ? c : 0;
            stz(cs_val, p, zbf, ldmix(vals, i, isbf));
        }
    }
}

// ---------------- weight fragment pre-layout (canonical bf16) ----------------
// B-frag (mfma_f32_16x16x32_bf16): lane l holds B[k=(l>>4)*8+j][n=l&15], j=0..7.

__global__ void w1frag_kernel(const void* __restrict__ W1, ushort_t* __restrict__ w1f,
                              const int* __restrict__ flag) {
    int t = blockIdx.x * 256 + threadIdx.x;  // 16384 total
    if (t >= 16 * 16 * 64) return;
    int isbf = flag[0];
    int l = t & 63, nt = (t >> 6) & 15, kb = t >> 10;
    ushort_t tmp[8];
#pragma unroll
    for (int j = 0; j < 8; j++) {
        int k = kb * 32 + (l >> 4) * 8 + j;
        int nn = nt * 16 + (l & 15);
        tmp[j] = f2b(ldmix(W1, (size_t)k * NHID + nn, isbf));
    }
    *(short8*)(w1f + (size_t)t * 8) = *(short8*)tmp;
}

__global__ void w2frag_kernel(const void* __restrict__ W2, ushort_t* __restrict__ w2f,
                              const int* __restrict__ flag) {
    int t = blockIdx.x * 256 + threadIdx.x;  // 1536 total
    if (t >= 8 * 3 * 64) return;
    int isbf = flag[0];
    int l = t % 64;
    int nt = (t / 64) % 3;
    int kb = t / 192;
    ushort_t tmp[8];
#pragma unroll
    for (int j = 0; j < 8; j++) {
        int k = kb * 32 + (l >> 4) * 8 + j;
        int nn = nt * 16 + (l & 15);
        tmp[j] = (nn < NCLASS) ? f2b(ldmix(W2, (size_t)k * NCLASS + nn, isbf)) : (ushort_t)0;
    }
    *(short8*)(w2f + (size_t)t * 8) = *(short8*)tmp;
}

// ---------------- fused MLP: h = relu(x@W1+b1)@W2 + b2 ----------------

__global__ __launch_bounds__(256) void mlp_kernel(const void* __restrict__ x,
                                                  const ushort_t* __restrict__ w1f,
                                                  const ushort_t* __restrict__ w2f,
                                                  const void* __restrict__ b1,
                                                  const void* __restrict__ b2,
                                                  void* __restrict__ h,
                                                  const int* __restrict__ flag, int zbf, int n) {
    __shared__ ushort_t Alds[64][40];   // 80B pitch
    __shared__ ushort_t Hlds[64][264];  // 528B pitch, 256 cols used
    const int t = threadIdx.x;
    const int isbf = flag[0];
    const int wv = t >> 6, l = t & 63;
    const int lq = l >> 4, lr = l & 15;
    const int m0 = blockIdx.x * 64;

    f32x4 acc[16];
#pragma unroll
    for (int i = 0; i < 16; i++) acc[i] = (f32x4){0.f, 0.f, 0.f, 0.f};

    const int rS = t >> 2, qS = t & 3;
    int rowS = m0 + rS;
    if (rowS > n - 1) rowS = n - 1;
    const size_t xbase = (size_t)rowS * NFEAT + qS * 8;
    const ushort_t* aldsp = &Alds[wv * 16 + lr][lq * 8];

    for (int kb = 0; kb < 16; kb++) {
        short8 av;
        if (isbf) {
            av = *(const short8*)((const ushort_t*)x + xbase + kb * 32);
#pragma unroll
            for (int j = 0; j < 8; j++) {
                ushort_t u = (ushort_t)av[j];
                if ((u & 0x7F80u) == 0x7F80u) av[j] = 0;
            }
        } else {
            const float* xf = (const float*)x + xbase + kb * 32;
            f32x4 a0 = *(const f32x4*)xf;
            f32x4 a1 = *(const f32x4*)(xf + 4);
#pragma unroll
            for (int j = 0; j < 4; j++) {
                av[j] = (short)f2b(a0[j]);
                av[4 + j] = (short)f2b(a1[j]);
            }
        }
        *(short8*)&Alds[rS][qS * 8] = av;
        __syncthreads();
        short8 afrag = *(const short8*)aldsp;
        const ushort_t* bp = w1f + ((size_t)(kb * 16) * 64 + l) * 8;
#pragma unroll
        for (int nt = 0; nt < 16; nt++) {
            short8 bfrag = *(const short8*)(bp + (size_t)nt * 64 * 8);
            acc[nt] = __builtin_amdgcn_mfma_f32_16x16x32_bf16(afrag, bfrag, acc[nt], 0, 0, 0);
        }
        __syncthreads();
    }

    float bias1 = ldmix(b1, 0, isbf);
#pragma unroll
    for (int nt = 0; nt < 16; nt++) {
#pragma unroll
        for (int i = 0; i < 4; i++) {
            float v = acc[nt][i] + bias1;
            v = fmaxf(v, 0.f);
            Hlds[wv * 16 + lq * 4 + i][nt * 16 + lr] = f2b(v);
        }
    }
    __syncthreads();

    f32x4 acc2[3];
#pragma unroll
    for (int i = 0; i < 3; i++) acc2[i] = (f32x4){0.f, 0.f, 0.f, 0.f};
    const ushort_t* hp = &Hlds[wv * 16 + lr][lq * 8];
#pragma unroll
    for (int kb = 0; kb < 8; kb++) {
        short8 afrag = *(const short8*)(hp + kb * 32);
#pragma unroll
        for (int nt = 0; nt < 3; nt++) {
            short8 bfrag = *(const short8*)(w2f + ((size_t)(kb * 3 + nt) * 64 + l) * 8);
            acc2[nt] = __builtin_amdgcn_mfma_f32_16x16x32_bf16(afrag, bfrag, acc2[nt], 0, 0, 0);
        }
    }

    float bias2 = ldmix(b2, 0, isbf);
#pragma unroll
    for (int nt = 0; nt < 3; nt++) {
#pragma unroll
        for (int i = 0; i < 4; i++) {
            int rowg = m0 + wv * 16 + lq * 4 + i;
            int colg = nt * 16 + lr;
            if (rowg < n && colg < NCLASS)
                stz(h, (size_t)rowg * NCLASS + colg, zbf, acc2[nt][i] + bias2);
        }
    }
}

// ---------------- propagation: zout = 0.9 * A zin + 0.1 * h ----------------
// one wave per node; lanes 0..39 = features. Inner loop unrolled x8 with the
// v=0-idle-lane trick: lanes >= m hold c=0,v=0, so over-issued iterations
// contribute 0 (and hit L1-hot row 0). 8 independent gathers in flight per
// group -> ~deg/8 latency stalls per node instead of ~deg.

template <int ZBF>
__global__ __launch_bounds__(256) void prop_kernel(const void* __restrict__ zin,
                                                   void* __restrict__ zout,
                                                   const void* __restrict__ h,
                                                   const int* __restrict__ row_start,
                                                   const int* __restrict__ deg,
                                                   const int* __restrict__ cs_col,
                                                   const void* __restrict__ cs_val, int n) {
    int w = blockIdx.x * 4 + (threadIdx.x >> 6);
    int lane = threadIdx.x & 63;
    if (w >= n) return;
    int start = row_start[w];
    int d = deg[w];
    const bool laneok = lane < NCLASS;
    float acc = 0.f;
    for (int base = 0; base < d; base += 64) {
        int m = d - base;
        if (m > 64) m = 64;
        int c = 0;
        float v = 0.f;
        if (lane < m) {
            size_t idx = (size_t)start + base + lane;
            c = cs_col[idx];
            v = ZBF ? b2f(((const ushort_t*)cs_val)[idx]) : ((const float*)cs_val)[idx];
        }
        for (int j = 0; j < m; j += 8) {
            int cc[8];
            float vv[8];
#pragma unroll
            for (int k = 0; k < 8; k++) {
                cc[k] = __shfl(c, j + k);
                vv[k] = __shfl(v, j + k);
            }
            if (laneok) {
                float zv[8];
#pragma unroll
                for (int k = 0; k < 8; k++) {
                    size_t zi = (size_t)cc[k] * NCLASS + lane;
                    zv[k] = ZBF ? b2f(((const ushort_t*)zin)[zi]) : ((const float*)zin)[zi];
                }
#pragma unroll
                for (int k = 0; k < 8; k++) acc += vv[k] * zv[k];
            }
        }
    }
    if (laneok) {
        float hv = ZBF ? b2f(((const ushort_t*)h)[(size_t)w * NCLASS + lane])
                       : ((const float*)h)[(size_t)w * NCLASS + lane];
        float r = 0.9f * acc + 0.1f * hv;
        if (ZBF) ((ushort_t*)zout)[(size_t)w * NCLASS + lane] = f2b(r);
        else ((float*)zout)[(size_t)w * NCLASS + lane] = r;
    }
}

// ---------------- log_softmax; out dtype follows detected input dtype ---------

__global__ __launch_bounds__(256) void lsm_kernel(const void* __restrict__ z,
                                                  void* __restrict__ out,
                                                  const int* __restrict__ flag, int zbf, int n) {
    int w = blockIdx.x * 4 + (threadIdx.x >> 6);
    int lane = threadIdx.x & 63;
    if (w >= n) return;
    int isbf = flag[0];
    float v = (lane < NCLASS) ? ldz(z, (size_t)w * NCLASS + lane, zbf) : -INFINITY;
    float m = v;
    for (int o = 32; o; o >>= 1) m = fmaxf(m, __shfl_xor(m, o));
    float e = (lane < NCLASS) ? __expf(v - m) : 0.f;
    float s = e;
    for (int o = 32; o; o >>= 1) s += __shfl_xor(s, o);
    if (lane < NCLASS) {
        float r = v - m - __logf(s);
        if (isbf) ((ushort_t*)out)[(size_t)w * NCLASS + lane] = f2b(r);
        else ((float*)out)[(size_t)w * NCLASS + lane] = r;
    }
}

// ---------------- launch ----------------

extern "C" void kernel_launch(void* const* d_in, const int* in_sizes, int n_in, void* d_out,
                              int out_size, void* d_ws, size_t ws_size, hipStream_t stream) {
    const void* x = d_in[0];
    const int* row = (const int*)d_in[1];
    const int* col = (const int*)d_in[2];
    const void* vals = d_in[3];
    const void* W1 = d_in[4];
    const void* b1 = d_in[5];
    const void* W2 = d_in[6];
    const void* b2 = d_in[7];

    const int N = in_sizes[0] / NFEAT;  // 100000
    const int E = in_sizes[1];          // 1600000

    const int roomy = (ws_size == 0) || (ws_size >= (size_t)66 * 1024 * 1024);
    const int zbf = roomy ? 0 : 1;
    const size_t ez = roomy ? 4 : 2;

    char* ws = (char*)d_ws;
    size_t off = 0;
    auto take = [&](size_t bytes) {
        size_t o = off;
        off = (off + bytes + 255) & ~(size_t)255;
        return (void*)(ws + o);
    };
    void* h = take((size_t)N * NCLASS * ez);
    void* zA = take((size_t)N * NCLASS * ez);
    void* zB = take((size_t)N * NCLASS * ez);
    int* cs_col = (int*)take((size_t)E * 4);
    void* cs_val = take((size_t)E * ez);
    int* deg = (int*)take((size_t)N * 4);
    int* row_start = (int*)take((size_t)N * 4);
    int* cursor = (int*)take((size_t)N * 4);
    ushort_t* w1f = (ushort_t*)take((size_t)NFEAT * NHID * 2);
    ushort_t* w2f = (ushort_t*)take((size_t)8 * 3 * 64 * 8 * 2);
    int* bsum = (int*)take(512 * 4);
    int* flag = (int*)take(256);

    const int NB = (N + 255) / 256;  // 391 <= 512
    const int EB = (E + 255) / 256;
    const int GB = (N + 63) / 64;
    const int PB = (N + 3) / 4;

    detect_kernel<<<1, 256, 0, stream>>>((const ushort_t*)x, flag);

    // CSR build (multi-block scan)
    zero_kernel<<<(N + 255) / 256, 256, 0, stream>>>(deg, N);
    hist_kernel<<<EB, 256, 0, stream>>>(row, deg, E, N);
    scan_blocksum<<<NB, 256, 0, stream>>>(deg, bsum, N);
    scan_bsum_excl<<<1, 512, 0, stream>>>(bsum, NB);
    scan_emit<<<NB, 256, 0, stream>>>(deg, bsum, row_start, cursor, N);
    scatter_kernel<<<EB, 256, 0, stream>>>(row, col, vals, cursor, cs_col, cs_val, flag, zbf, E,
                                           N);

    // weight fragments
    w1frag_kernel<<<64, 256, 0, stream>>>(W1, w1f, flag);
    w2frag_kernel<<<6, 256, 0, stream>>>(W2, w2f, flag);

    // fused MLP -> h
    mlp_kernel<<<GB, 256, 0, stream>>>(x, w1f, w2f, b1, b2, h, flag, zbf, N);

    // 10 propagation steps: h -> zA, then ping-pong zA/zB (ends in zB)
    if (zbf) {
        prop_kernel<1><<<PB, 256, 0, stream>>>(h, zA, h, row_start, deg, cs_col, cs_val, N);
        const void* zi = zA;
        void* zo = zB;
        for (int s = 1; s < 10; s++) {
            prop_kernel<1><<<PB, 256, 0, stream>>>(zi, zo, h, row_start, deg, cs_col, cs_val, N);
            const void* tmp = zi;
            zi = zo;
            zo = (void*)tmp;
        }
        lsm_kernel<<<PB, 256, 0, stream>>>(zi, d_out, flag, zbf, N);
    } else {
        prop_kernel<0><<<PB, 256, 0, stream>>>(h, zA, h, row_start, deg, cs_col, cs_val, N);
        const void* zi = zA;
        void* zo = zB;
        for (int s = 1; s < 10; s++) {
            prop_kernel<0><<<PB, 256, 0, stream>>>(zi, zo, h, row_start, deg, cs_col, cs_val, N);
            const void* tmp = zi;
            zi = zo;
            zo = (void*)tmp;
        }
        lsm_kernel<<<PB, 256, 0, stream>>>(zi, d_out, flag, zbf, N);
    }
}